// Round 14
// baseline (1060.877 us; speedup 1.0000x reference)
//
#include <hip/hip_runtime.h>
#include <cstdint>
#include <cstddef>

typedef unsigned short u16;
typedef unsigned char u8;
typedef unsigned int u32;

typedef short s16x8 __attribute__((ext_vector_type(8)));
typedef float f32x4 __attribute__((ext_vector_type(4)));

#define MF(a,b,c) __builtin_amdgcn_mfma_f32_16x16x32_bf16((a),(b),(c),0,0,0)

// ---------------- helpers ----------------
__device__ __forceinline__ float b2f(u16 h){ u32 u = ((u32)h)<<16; float f; __builtin_memcpy(&f,&u,4); return f; }
__device__ __forceinline__ u16 f2b(float x){ u32 u; __builtin_memcpy(&u,&x,4); u += 0x7fffu + ((u>>16)&1u); return (u16)(u>>16); }
__device__ __forceinline__ u16 f2h(float x){ _Float16 h = (_Float16)x; u16 u; __builtin_memcpy(&u,&h,2); return u; }
__device__ __forceinline__ float h2f(u16 v){ _Float16 h; __builtin_memcpy(&h,&v,2); return (float)h; }
__device__ __forceinline__ float sigf(float x){ return __builtin_amdgcn_rcpf(1.f+__expf(-x)); }
__device__ __forceinline__ float tanh2(float x){
  float ax=fabsf(x); float e=__expf(-2.f*ax);
  float r=(1.f-e)*__builtin_amdgcn_rcpf(1.f+e);
  return x<0.f? -r : r;
}

typedef __attribute__((address_space(1))) const void gvoid_t;
typedef __attribute__((address_space(3))) void lvoid_t;
__device__ __forceinline__ void gl_lds16(const u16* src, u16* dst){
  __builtin_amdgcn_global_load_lds((gvoid_t*)src, (lvoid_t*)dst, 16, 0, 0);
}

// coherent write-through store (no L2 dirtying; visible at coherence point)
__device__ __forceinline__ void st_u16_coh(u16* p, u16 v){
  asm volatile("global_store_short %0, %1, off sc0 sc1" :: "v"(p), "v"((u32)v) : "memory");
}
__device__ __forceinline__ void st_f32_coh(float* p, float v){
  asm volatile("global_store_dword %0, %1, off sc0 sc1" :: "v"(p), "v"(v) : "memory");
}
// pinned (non-rematerializable) 16B load
__device__ __forceinline__ s16x8 gload16(const u16* p){
  s16x8 r;
  asm volatile("global_load_dwordx4 %0, %1, off" : "=v"(r) : "v"(p) : "memory");
  return r;
}
// coherent 16B load: reads at coherence point (never stale)
__device__ __forceinline__ s16x8 gload16_coh(const u16* p){
  s16x8 r;
  asm volatile("global_load_dwordx4 %0, %1, off sc0 sc1" : "=v"(r) : "v"(p) : "memory");
  return r;
}

// ---------------- mask dtype detection + canonicalization ----------------
__global__ void detect_mask_mode(const u8* raw, int n, int* flag){
  __shared__ int cnt;
  int tid = threadIdx.x;
  if(tid==0) cnt=0;
  __syncthreads();
  int c=0;
  for(int i=tid;i<n;i+=blockDim.x) c += (raw[i]!=0);
  atomicAdd(&cnt, c);
  __syncthreads();
  if(tid==0) *flag = (cnt > (n>>2)) ? 1 : 0;  // 1 => byte-per-element layout
}

__global__ void convert_masks(const void* done_raw, const void* main_raw, u8* done_u8, u8* main_u8, int n, const int* flag){
  int mode = *flag;
  for(int i = blockIdx.x*blockDim.x + threadIdx.x; i<n; i += gridDim.x*blockDim.x){
    u8 d, m;
    if(mode){ d = ((const u8*)done_raw)[i]!=0; m = ((const u8*)main_raw)[i]!=0; }
    else    { d = ((const int*)done_raw)[i]!=0; m = ((const int*)main_raw)[i]!=0; }
    done_u8[i]=d; main_u8[i]=m;
  }
}

__global__ void zero_flags(int* p, int n){
  int i = blockIdx.x*blockDim.x + threadIdx.x;
  if(i<n) p[i]=0;
}

// ---------------- conversions ----------------
__global__ void cvt_f32_bf16(const float* __restrict__ in, u16* __restrict__ out, int n4){
  int i = blockIdx.x*blockDim.x + threadIdx.x;
  if(i < n4){
    float4 v = ((const float4*)in)[i];
    ushort4 o;
    o.x=f2b(v.x); o.y=f2b(v.y); o.z=f2b(v.z); o.w=f2b(v.w);
    ((ushort4*)out)[i]=o;
  }
}

// in [R][C] f32  ->  out [C][R] bf16
__global__ void transpose_to_bf16(const float* __restrict__ in, u16* __restrict__ out, int R, int C){
  __shared__ float tile[64][65];
  int c0 = blockIdx.x*64, r0 = blockIdx.y*64;
  int tx = threadIdx.x & 63, ty = threadIdx.x >> 6;   // 256 threads
  for(int i=ty;i<64;i+=4) tile[i][tx] = in[(size_t)(r0+i)*C + c0 + tx];
  __syncthreads();
  for(int i=ty;i<64;i+=4) out[(size_t)(c0+i)*R + r0 + tx] = f2b(tile[tx][i]);
}

__global__ void init_hsel(const float* __restrict__ h1in, const float* __restrict__ h2in,
                          const u8* __restrict__ mmain, u16* __restrict__ hsel0){
  int i = blockIdx.x*blockDim.x + threadIdx.x;
  if(i < 256*1024){
    int row = i >> 10;
    hsel0[i] = f2b(mmain[row] ? h1in[i] : h2in[i]);
  }
}

// ---------------- phase 1: Zx = x @ Wi + b  (BK=64, swizzled LDS, f16 out) ----------------
// LDS layout: [row 0..127][phys slot 0..7], 16B per slot; phys = logical ^ (row&7).
// Realized via pre-swizzled GLOBAL source + swizzled LDS read (both-sides involution,
// linear global_load_lds dest). Within a row the permuted slots cover the same 128B
// segment -> coalescing preserved. MFMA reads: 2 lanes/bank-group (free).
__global__ __launch_bounds__(256) void gemm_zx(const u16* __restrict__ A, const u16* __restrict__ Bt,
                                               const float* __restrict__ bias, u16* __restrict__ C){
  __shared__ u16 As[8192];   // 16 KB: 128 rows x 8 slots x 8 u16
  __shared__ u16 Bs[8192];
  const int nbx = 32;
  const int nwg = 8192;
  int gid = blockIdx.x;
  int per = nwg>>3;
  int g2 = (gid&7)*per + (gid>>3);   // XCD-contiguous remap (bijective: nwg%8==0)
  int tpg = 8*nbx;
  int grp = g2/tpg, w = g2%tpg;
  int brow = grp*8 + (w & 7);
  int bcol = w >> 3;
  int row0 = brow<<7, col0 = bcol<<7;

  int tid=threadIdx.x, wid=tid>>6, lane=tid&63;
  int l15=lane&15, hi=lane>>4;
  int wm=(wid>>1)<<6, wn=(wid&1)<<6;
  const int l7 = l15 & 7;            // row&7 for all fragment rows (wm,m*16 are mult of 8)

  f32x4 acc[4][4];
  #pragma unroll
  for(int m=0;m<4;m++)
    #pragma unroll
    for(int n=0;n<4;n++) acc[m][n]=(f32x4){0.f,0.f,0.f,0.f};

  for(int k0=0;k0<1024;k0+=64){
    __syncthreads();
    #pragma unroll
    for(int q=0;q<4;q++){
      int cb = wid*256 + q*64;       // 64 chunks = 1KB linear dest per instruction
      int ch = cb + lane;
      int r = ch>>3, p = ch&7;
      gl_lds16(A + (size_t)(row0+r)*1024 + k0 + ((p^(r&7))<<3), &As[cb*8]);
    }
    #pragma unroll
    for(int q=0;q<4;q++){
      int cb = wid*256 + q*64;
      int ch = cb + lane;
      int r = ch>>3, p = ch&7;
      gl_lds16(Bt + (size_t)(col0+r)*1024 + k0 + ((p^(r&7))<<3), &Bs[cb*8]);
    }
    __syncthreads();
    #pragma unroll
    for(int kk=0;kk<2;kk++){
      int sp = (kk*4 + hi) ^ l7;     // phys slot (logical kk*4+hi)
      s16x8 a[4], b[4];
      #pragma unroll
      for(int m=0;m<4;m++) a[m] = *(const s16x8*)&As[(wm+m*16+l15)*64 + sp*8];
      #pragma unroll
      for(int n=0;n<4;n++) b[n] = *(const s16x8*)&Bs[(wn+n*16+l15)*64 + sp*8];
      #pragma unroll
      for(int m=0;m<4;m++)
        #pragma unroll
        for(int n=0;n<4;n++)
          acc[m][n] = MF(a[m],b[n],acc[m][n]);
    }
  }
  #pragma unroll
  for(int m=0;m<4;m++){
    #pragma unroll
    for(int n=0;n<4;n++){
      int c = col0+wn+n*16+l15;
      float bv = bias[c];
      #pragma unroll
      for(int j=0;j<4;j++){
        int r = row0+wm+m*16+hi*4+j;
        C[(size_t)r*4096+c] = f2h(acc[m][n][j] + bv);
      }
    }
  }
}

// ---------------- phase 2: persistent recurrent kernel (R12-exact) ----------------
__global__ __launch_bounds__(512) __attribute__((amdgpu_waves_per_eu(2,2)))
void lstm_persist(
    const u16* __restrict__ Zx, const u16* __restrict__ Wht,
    u16* __restrict__ hs0, u16* __restrict__ hs1,
    const float* __restrict__ c1i, const float* __restrict__ h1i,
    const float* __restrict__ c2i, const float* __restrict__ h2i,
    const u8* __restrict__ mdone, const u8* __restrict__ mmain,
    float* __restrict__ out, int* __restrict__ ready)
{
  __shared__ u16 As[32768];            // 64 KB: 128 chunks x [32 rows x 16B], XOR-swizzled
  __shared__ float zpart[4*2*32*33];   // 33 KB: [gate][kg][row][33] partial sums

  const int bid = blockIdx.x;
  const int rg = bid & 7, jg = bid >> 3;
  const int r0 = rg << 5, j0 = jg << 5;
  const int tid = threadIdx.x, wid = tid >> 6, lane = tid & 63;
  const int l15 = lane & 15, hi = lane >> 4;
  const int gate = wid >> 1, kg = wid & 1;
  const int srow = tid >> 4, sc16 = tid & 15;   // staging: row 0..31, col16 0..15
  const int erow = tid >> 5, ecol = tid & 31;   // epilogue: rows, 32 cols

  // ---- Wh^T fragments: this wave's (gate, K-half) x 32 cols: 128 VGPRs ----
  s16x8 breg[2][16];
  {
    #pragma unroll
    for(int n=0;n<2;n++){
      const u16* wp = Wht + ((size_t)(gate*1024 + j0 + n*16 + l15))*1024 + kg*512 + hi*8;
      #pragma unroll
      for(int kk=0;kk<16;kk++) breg[n][kk] = gload16(wp + kk*32);
    }
    asm volatile("s_waitcnt vmcnt(0)" ::: "memory");
    __builtin_amdgcn_sched_barrier(0);
  }

  // ---- states into registers (thread-stationary across all 128 steps) ----
  float c1r[2],c2r[2],h1r[2],h2r[2];
  #pragma unroll
  for(int e=0;e<2;e++){
    size_t sidx = (size_t)(r0 + e*16 + erow)*1024 + j0 + ecol;
    c1r[e]=c1i[sidx]; c2r[e]=c2i[sidx]; h1r[e]=h1i[sidx]; h2r[e]=h2i[sidx];
  }

  int* flag = ready + rg*32;    // 128B-spaced per-rg counters

  for(int t=0;t<128;t++){
    // ---- prefetch step-local immutable inputs (f16 Zx is L3-resident) ----
    float zr[4][2]; u8 md[2], mm[2], mm2[2];
    #pragma unroll
    for(int e=0;e<2;e++){
      int gb = t*256 + r0 + e*16 + erow;
      size_t base = (size_t)gb*4096 + j0 + ecol;
      #pragma unroll
      for(int g=0; g<4; g++)
        zr[g][e] = h2f(Zx[base + g*1024]);
      md[e]=mdone[gb]; mm[e]=mmain[gb];
      mm2[e] = (t<127) ? mmain[gb+256] : (u8)0;
    }

    // ---- chain wait (single spinner; others park at the barrier) ----
    if(t>0 && tid==0){
      while(__hip_atomic_load(flag, __ATOMIC_RELAXED, __HIP_MEMORY_SCOPE_AGENT) < 32*t)
        __builtin_amdgcn_s_sleep(1);
    }
    __syncthreads();
    __builtin_amdgcn_sched_barrier(0);

    const u16* hin = (t&1) ? hs1 : hs0;
    u16* hout = (t&1) ? hs0 : hs1;

    // ---- stage h tile: 8 coherent 16B loads/thread -> swizzled LDS,
    //      ds_writes interleaved with counted vmcnt ----
    {
      const u16* hrow = hin + (size_t)(r0+srow)*1024;
      s16x8 v[8];
      #pragma unroll
      for(int kc=0;kc<8;kc++) v[kc] = gload16_coh(hrow + (kc*16+sc16)*8);
      asm volatile("s_waitcnt vmcnt(4)" ::: "memory");
      #pragma unroll
      for(int kc=0;kc<4;kc++){
        int chunk = kc*16+sc16;
        *(s16x8*)&As[chunk*256 + ((srow ^ (chunk&7))<<3)] = v[kc];
      }
      asm volatile("s_waitcnt vmcnt(0)" ::: "memory");
      #pragma unroll
      for(int kc=4;kc<8;kc++){
        int chunk = kc*16+sc16;
        *(s16x8*)&As[chunk*256 + ((srow ^ (chunk&7))<<3)] = v[kc];
      }
    }
    __syncthreads();   // tile staged

    // ---- recurrent GEMM: this wave's K-half, 64 MFMA, B from registers ----
    f32x4 acc[2][2];
    #pragma unroll
    for(int m=0;m<2;m++)
      #pragma unroll
      for(int n=0;n<2;n++) acc[m][n]=(f32x4){0.f,0.f,0.f,0.f};
    #pragma unroll
    for(int kk=0;kk<16;kk++){
      int c0 = (kg*16 + kk)*4 + hi;                 // 16B chunk 0..127
      s16x8 a0 = *(const s16x8*)&As[c0*256 + ((l15      ^ (c0&7))<<3)];
      s16x8 a1 = *(const s16x8*)&As[c0*256 + (((16+l15) ^ (c0&7))<<3)];
      acc[0][0] = MF(a0, breg[0][kk], acc[0][0]);
      acc[0][1] = MF(a0, breg[1][kk], acc[0][1]);
      acc[1][0] = MF(a1, breg[0][kk], acc[1][0]);
      acc[1][1] = MF(a1, breg[1][kk], acc[1][1]);
    }
    // no barrier needed: zpart is a separate LDS region

    // ---- K-half partial exchange: zpart[gate][kg][row][33] ----
    #pragma unroll
    for(int m=0;m<2;m++)
      #pragma unroll
      for(int n=0;n<2;n++)
        #pragma unroll
        for(int j=0;j<4;j++){
          int row = m*16 + hi*4 + j;
          zpart[((gate*2+kg)*32 + row)*33 + n*16 + l15] = acc[m][n][j];
        }
    __syncthreads();

    // ---- epilogue: sum K-halves, gates, state update; h stores first ----
    float nhv[2];
    #pragma unroll
    for(int e=0;e<2;e++){
      int row = e*16 + erow;
      float zi  = zr[0][e] + zpart[((0)*32+row)*33 + ecol] + zpart[((1)*32+row)*33 + ecol];
      float zf_ = zr[1][e] + zpart[((2)*32+row)*33 + ecol] + zpart[((3)*32+row)*33 + ecol];
      float zg  = zr[2][e] + zpart[((4)*32+row)*33 + ecol] + zpart[((5)*32+row)*33 + ecol];
      float zo  = zr[3][e] + zpart[((6)*32+row)*33 + ecol] + zpart[((7)*32+row)*33 + ecol];
      bool m_ = mm[e]!=0, d_ = md[e]!=0;
      float co = m_ ? c1r[e] : c2r[e];
      float nc = sigf(zf_)*co + sigf(zi)*tanh2(zg);
      float nhx = sigf(zo)*tanh2(nc);
      nhv[e] = nhx;
      float n1c = m_?nc:c1r[e], n2c = m_?c2r[e]:nc;
      float n1h = m_?nhx:h1r[e], n2h = m_?h2r[e]:nhx;
      if(d_){ n1c=0.f; n2c=0.f; n1h=0.f; n2h=0.f; }
      c1r[e]=n1c; c2r[e]=n2c; h1r[e]=n1h; h2r[e]=n2h;
      if(t<127)
        st_u16_coh(&hout[(size_t)(r0+row)*1024 + j0 + ecol], f2b(mm2[e] ? n1h : n2h));
    }
    asm volatile("s_waitcnt vmcnt(0)" ::: "memory");   // h at coherence point
    __syncthreads();
    if(t<127 && tid==0)
      __hip_atomic_fetch_add(flag, 1, __ATOMIC_RELAXED, __HIP_MEMORY_SCOPE_AGENT);

    // ---- out store off the critical path (drains during next spin) ----
    #pragma unroll
    for(int e=0;e<2;e++){
      int gb = t*256 + r0 + e*16 + erow;
      st_f32_coh(&out[(size_t)gb*1024 + j0 + ecol], nhv[e]);
    }
  }
}

// ---------------- host ----------------
extern "C" void kernel_launch(void* const* d_in, const int* in_sizes, int n_in,
                              void* d_out, int out_size, void* d_ws, size_t ws_size,
                              hipStream_t stream){
  const float* x   = (const float*)d_in[0];
  const float* c1i = (const float*)d_in[1];
  const float* h1i = (const float*)d_in[2];
  const float* c2i = (const float*)d_in[3];
  const float* h2i = (const float*)d_in[4];
  const float* Wi  = (const float*)d_in[5];
  const float* Wh  = (const float*)d_in[6];
  const float* bias= (const float*)d_in[7];
  const void* done_raw = d_in[8];
  const void* main_raw = d_in[9];
  float* out = (float*)d_out;

  char* ws = (char*)d_ws;
  size_t off=0;
  auto alloc=[&](size_t sz)->char*{ char* p = ws+off; off += (sz+255)&~(size_t)255; return p; };

  u16* xb   = (u16*)alloc(33554432ull*2);        // x as bf16 [32768][1024]
  u16* WiT  = (u16*)alloc(4096ull*1024*2);       // Wi^T bf16 [4096][1024]
  u16* WhT  = (u16*)alloc(4096ull*1024*2);       // Wh^T bf16 [4096][1024]
  u16* hs0  = (u16*)alloc(262144ull*2);
  u16* hs1  = (u16*)alloc(262144ull*2);
  u8* dmask = (u8*)alloc(32768);
  u8* mmask = (u8*)alloc(32768);
  int* flag = (int*)alloc(256);
  int* ready= (int*)alloc(1024);
  u16* Zx   = (u16*)alloc(268435456ull);         // Zx f16 [32768][4096] -- L3-resident

  detect_mask_mode<<<1,256,0,stream>>>((const u8*)done_raw, 32768, flag);
  convert_masks<<<64,256,0,stream>>>(done_raw, main_raw, dmask, mmask, 32768, flag);
  cvt_f32_bf16<<<32768,256,0,stream>>>(x, xb, 8388608);
  transpose_to_bf16<<<dim3(64,16),256,0,stream>>>(Wi, WiT, 1024, 4096);
  transpose_to_bf16<<<dim3(64,16),256,0,stream>>>(Wh, WhT, 1024, 4096);
  init_hsel<<<1024,256,0,stream>>>(h1i, h2i, mmask, hs0);
  zero_flags<<<1,256,0,stream>>>(ready, 256);

  gemm_zx<<<8192,256,0,stream>>>(xb, WiT, bias, Zx);

  lstm_persist<<<256,512,0,stream>>>(Zx,WhT,hs0,hs1,c1i,h1i,c2i,h2i,dmask,mmask,out,ready);
}

// Round 15
// 1053.740 us; speedup vs baseline: 1.0068x; 1.0068x over previous
//
#include <hip/hip_runtime.h>
#include <cstdint>
#include <cstddef>

typedef unsigned short u16;
typedef unsigned char u8;
typedef unsigned int u32;

typedef short s16x8 __attribute__((ext_vector_type(8)));
typedef float f32x4 __attribute__((ext_vector_type(4)));

#define MF(a,b,c) __builtin_amdgcn_mfma_f32_16x16x32_bf16((a),(b),(c),0,0,0)

// ---------------- helpers ----------------
__device__ __forceinline__ float b2f(u16 h){ u32 u = ((u32)h)<<16; float f; __builtin_memcpy(&f,&u,4); return f; }
__device__ __forceinline__ u16 f2b(float x){ u32 u; __builtin_memcpy(&u,&x,4); u += 0x7fffu + ((u>>16)&1u); return (u16)(u>>16); }
__device__ __forceinline__ u16 f2h(float x){ _Float16 h = (_Float16)x; u16 u; __builtin_memcpy(&u,&h,2); return u; }
__device__ __forceinline__ float h2f(u16 v){ _Float16 h; __builtin_memcpy(&h,&v,2); return (float)h; }
__device__ __forceinline__ float sigf(float x){ return __builtin_amdgcn_rcpf(1.f+__expf(-x)); }
__device__ __forceinline__ float tanh2(float x){
  float ax=fabsf(x); float e=__expf(-2.f*ax);
  float r=(1.f-e)*__builtin_amdgcn_rcpf(1.f+e);
  return x<0.f? -r : r;
}

typedef __attribute__((address_space(1))) const void gvoid_t;
typedef __attribute__((address_space(3))) void lvoid_t;
__device__ __forceinline__ void gl_lds16(const u16* src, u16* dst){
  __builtin_amdgcn_global_load_lds((gvoid_t*)src, (lvoid_t*)dst, 16, 0, 0);
}

// coherent write-through store (no L2 dirtying; visible at coherence point)
__device__ __forceinline__ void st_u16_coh(u16* p, u16 v){
  asm volatile("global_store_short %0, %1, off sc0 sc1" :: "v"(p), "v"((u32)v) : "memory");
}
__device__ __forceinline__ void st_f32_coh(float* p, float v){
  asm volatile("global_store_dword %0, %1, off sc0 sc1" :: "v"(p), "v"(v) : "memory");
}
// pinned (non-rematerializable) 16B load
__device__ __forceinline__ s16x8 gload16(const u16* p){
  s16x8 r;
  asm volatile("global_load_dwordx4 %0, %1, off" : "=v"(r) : "v"(p) : "memory");
  return r;
}
// coherent 16B load: reads at coherence point (never stale)
__device__ __forceinline__ s16x8 gload16_coh(const u16* p){
  s16x8 r;
  asm volatile("global_load_dwordx4 %0, %1, off sc0 sc1" : "=v"(r) : "v"(p) : "memory");
  return r;
}

// ---------------- mask dtype detection + canonicalization ----------------
__global__ void detect_mask_mode(const u8* raw, int n, int* flag){
  __shared__ int cnt;
  int tid = threadIdx.x;
  if(tid==0) cnt=0;
  __syncthreads();
  int c=0;
  for(int i=tid;i<n;i+=blockDim.x) c += (raw[i]!=0);
  atomicAdd(&cnt, c);
  __syncthreads();
  if(tid==0) *flag = (cnt > (n>>2)) ? 1 : 0;  // 1 => byte-per-element layout
}

__global__ void convert_masks(const void* done_raw, const void* main_raw, u8* done_u8, u8* main_u8, int n, const int* flag){
  int mode = *flag;
  for(int i = blockIdx.x*blockDim.x + threadIdx.x; i<n; i += gridDim.x*blockDim.x){
    u8 d, m;
    if(mode){ d = ((const u8*)done_raw)[i]!=0; m = ((const u8*)main_raw)[i]!=0; }
    else    { d = ((const int*)done_raw)[i]!=0; m = ((const int*)main_raw)[i]!=0; }
    done_u8[i]=d; main_u8[i]=m;
  }
}

__global__ void zero_flags(int* p, int n){
  int i = blockIdx.x*blockDim.x + threadIdx.x;
  if(i<n) p[i]=0;
}

// ---------------- conversions ----------------
__global__ void cvt_f32_bf16(const float* __restrict__ in, u16* __restrict__ out, int n4){
  int i = blockIdx.x*blockDim.x + threadIdx.x;
  if(i < n4){
    float4 v = ((const float4*)in)[i];
    ushort4 o;
    o.x=f2b(v.x); o.y=f2b(v.y); o.z=f2b(v.z); o.w=f2b(v.w);
    ((ushort4*)out)[i]=o;
  }
}

// in [R][C] f32  ->  out [C][R] bf16
__global__ void transpose_to_bf16(const float* __restrict__ in, u16* __restrict__ out, int R, int C){
  __shared__ float tile[64][65];
  int c0 = blockIdx.x*64, r0 = blockIdx.y*64;
  int tx = threadIdx.x & 63, ty = threadIdx.x >> 6;   // 256 threads
  for(int i=ty;i<64;i+=4) tile[i][tx] = in[(size_t)(r0+i)*C + c0 + tx];
  __syncthreads();
  for(int i=ty;i<64;i+=4) out[(size_t)(c0+i)*R + r0 + tx] = f2b(tile[tx][i]);
}

__global__ void init_hsel(const float* __restrict__ h1in, const float* __restrict__ h2in,
                          const u8* __restrict__ mmain, u16* __restrict__ hsel0){
  int i = blockIdx.x*blockDim.x + threadIdx.x;
  if(i < 256*1024){
    int row = i >> 10;
    hsel0[i] = f2b(mmain[row] ? h1in[i] : h2in[i]);
  }
}

// ---------------- phase 1: Zx = x @ Wi + b ----------------
// 256x256 tile, BK=32, QUAD-buffered LDS (4 x 32KB), prefetch distance 3 K-tiles:
// per K-tile: vmcnt(8) [2 newer tiles stay in flight] -> raw s_barrier (avoids
// compiler's vmcnt(0) drain at __syncthreads -- the m97 stall) -> issue stage of
// kt+3 into buffer freed at this barrier -> 12 ds_read_b128 -> 32 MFMA (setprio).
// LDS swizzle: slot ^= (row>>1)&3, applied on pre-swizzled GLOBAL source (linear
// global_load_lds dest) and identically on reads -> 2-way (free) bank pattern.
__global__ __launch_bounds__(512) __attribute__((amdgpu_waves_per_eu(2,2)))
void gemm_zx(const u16* __restrict__ A, const u16* __restrict__ Bt,
             const float* __restrict__ bias, u16* __restrict__ C){
  __shared__ u16 As[32768];   // 4 bufs x 256 rows x 4 slots x 8 u16 = 64 KB
  __shared__ u16 Bs[32768];   // 64 KB
  const int nbx = 16;                 // N/256
  const int nwg = 2048;               // (M/256)*(N/256), divisible by 8
  int gid = blockIdx.x;
  int per = nwg>>3;
  int g2 = (gid&7)*per + (gid>>3);    // XCD-contiguous remap (bijective)
  int tpg = 8*nbx;                    // 128
  int grp = g2/tpg, w = g2%tpg;
  int brow = grp*8 + (w & 7);         // 0..127
  int bcol = w >> 3;                  // 0..15
  int row0 = brow<<8, col0 = bcol<<8;

  int tid=threadIdx.x, wid=tid>>6, lane=tid&63;
  int l15=lane&15, hi=lane>>4;
  int wm=(wid>>2)<<7;                 // 0 or 128 (row half)
  int wn=(wid&3)<<6;                  // 0/64/128/192 (col quarter)

  // t-invariant read offsets (bytes within one 16KB buffer)
  int fsw = (l15>>1)&3;               // (row>>1)&3 with row = 16k + l15
  u32 aoff = (u32)((wm + l15)*64 + ((hi ^ fsw)<<4));
  u32 boff = (u32)((wn + l15)*64 + ((hi ^ fsw)<<4));

  f32x4 acc[8][4];
  #pragma unroll
  for(int m=0;m<8;m++)
    #pragma unroll
    for(int n=0;n<4;n++) acc[m][n]=(f32x4){0.f,0.f,0.f,0.f};

  auto stage=[&](int kt){
    int k0 = kt<<5;
    int bo = (kt&3)<<13;              // u16 offset of buffer (8192 u16 = 16KB)
    #pragma unroll
    for(int q=0;q<2;q++){
      int ch = q*512 + tid;           // 0..1023
      int r = ch>>2, p = ch&3;
      int ks = p ^ ((r>>1)&3);        // pre-swizzled source k-slot
      gl_lds16(A + (size_t)(row0+r)*1024 + k0 + ks*8, &As[bo + ch*8]);
    }
    #pragma unroll
    for(int q=0;q<2;q++){
      int ch = q*512 + tid;
      int r = ch>>2, p = ch&3;
      int ks = p ^ ((r>>1)&3);
      gl_lds16(Bt + (size_t)(col0+r)*1024 + k0 + ks*8, &Bs[bo + ch*8]);
    }
  };

  stage(0); stage(1); stage(2);       // 12 loads/thread outstanding

  #define GITER(KT, WAITSTR, DOISSUE) { \
    asm volatile(WAITSTR ::: "memory"); \
    __builtin_amdgcn_sched_barrier(0); \
    __builtin_amdgcn_s_barrier(); \
    __builtin_amdgcn_sched_barrier(0); \
    if(DOISSUE) stage((KT)+3); \
    const char* pa = (const char*)As + (((KT)&3)<<14); \
    const char* pb = (const char*)Bs + (((KT)&3)<<14); \
    s16x8 af[8], bf[4]; \
    _Pragma("unroll") \
    for(int m=0;m<8;m++) af[m] = *(const s16x8*)(pa + aoff + m*1024); \
    _Pragma("unroll") \
    for(int n=0;n<4;n++) bf[n] = *(const s16x8*)(pb + boff + n*1024); \
    __builtin_amdgcn_s_setprio(1); \
    _Pragma("unroll") \
    for(int m=0;m<8;m++){ \
      _Pragma("unroll") \
      for(int n=0;n<4;n++) acc[m][n] = MF(af[m], bf[n], acc[m][n]); } \
    __builtin_amdgcn_s_setprio(0); \
  }

  #pragma unroll 1
  for(int kt=0; kt<30; kt++){
    GITER(kt, "s_waitcnt vmcnt(8)", (kt<29))
  }
  GITER(30, "s_waitcnt vmcnt(4)", false)
  GITER(31, "s_waitcnt vmcnt(0)", false)
  #undef GITER

  // epilogue: bias + f16 store
  #pragma unroll
  for(int m=0;m<8;m++){
    #pragma unroll
    for(int n=0;n<4;n++){
      int c = col0 + wn + n*16 + l15;
      float bv = bias[c];
      #pragma unroll
      for(int j=0;j<4;j++){
        int r = row0 + wm + m*16 + hi*4 + j;
        C[(size_t)r*4096 + c] = f2h(acc[m][n][j] + bv);
      }
    }
  }
}

// ---------------- phase 2: persistent recurrent kernel (R12-exact) ----------------
__global__ __launch_bounds__(512) __attribute__((amdgpu_waves_per_eu(2,2)))
void lstm_persist(
    const u16* __restrict__ Zx, const u16* __restrict__ Wht,
    u16* __restrict__ hs0, u16* __restrict__ hs1,
    const float* __restrict__ c1i, const float* __restrict__ h1i,
    const float* __restrict__ c2i, const float* __restrict__ h2i,
    const u8* __restrict__ mdone, const u8* __restrict__ mmain,
    float* __restrict__ out, int* __restrict__ ready)
{
  __shared__ u16 As[32768];            // 64 KB: 128 chunks x [32 rows x 16B], XOR-swizzled
  __shared__ float zpart[4*2*32*33];   // 33 KB: [gate][kg][row][33] partial sums

  const int bid = blockIdx.x;
  const int rg = bid & 7, jg = bid >> 3;
  const int r0 = rg << 5, j0 = jg << 5;
  const int tid = threadIdx.x, wid = tid >> 6, lane = tid & 63;
  const int l15 = lane & 15, hi = lane >> 4;
  const int gate = wid >> 1, kg = wid & 1;
  const int srow = tid >> 4, sc16 = tid & 15;   // staging: row 0..31, col16 0..15
  const int erow = tid >> 5, ecol = tid & 31;   // epilogue: rows, 32 cols

  // ---- Wh^T fragments: this wave's (gate, K-half) x 32 cols: 128 VGPRs ----
  s16x8 breg[2][16];
  {
    #pragma unroll
    for(int n=0;n<2;n++){
      const u16* wp = Wht + ((size_t)(gate*1024 + j0 + n*16 + l15))*1024 + kg*512 + hi*8;
      #pragma unroll
      for(int kk=0;kk<16;kk++) breg[n][kk] = gload16(wp + kk*32);
    }
    asm volatile("s_waitcnt vmcnt(0)" ::: "memory");
    __builtin_amdgcn_sched_barrier(0);
  }

  // ---- states into registers (thread-stationary across all 128 steps) ----
  float c1r[2],c2r[2],h1r[2],h2r[2];
  #pragma unroll
  for(int e=0;e<2;e++){
    size_t sidx = (size_t)(r0 + e*16 + erow)*1024 + j0 + ecol;
    c1r[e]=c1i[sidx]; c2r[e]=c2i[sidx]; h1r[e]=h1i[sidx]; h2r[e]=h2i[sidx];
  }

  int* flag = ready + rg*32;    // 128B-spaced per-rg counters

  for(int t=0;t<128;t++){
    // ---- prefetch step-local immutable inputs (f16 Zx is L3-resident) ----
    float zr[4][2]; u8 md[2], mm[2], mm2[2];
    #pragma unroll
    for(int e=0;e<2;e++){
      int gb = t*256 + r0 + e*16 + erow;
      size_t base = (size_t)gb*4096 + j0 + ecol;
      #pragma unroll
      for(int g=0; g<4; g++)
        zr[g][e] = h2f(Zx[base + g*1024]);
      md[e]=mdone[gb]; mm[e]=mmain[gb];
      mm2[e] = (t<127) ? mmain[gb+256] : (u8)0;
    }

    // ---- chain wait (single spinner; others park at the barrier) ----
    if(t>0 && tid==0){
      while(__hip_atomic_load(flag, __ATOMIC_RELAXED, __HIP_MEMORY_SCOPE_AGENT) < 32*t)
        __builtin_amdgcn_s_sleep(1);
    }
    __syncthreads();
    __builtin_amdgcn_sched_barrier(0);

    const u16* hin = (t&1) ? hs1 : hs0;
    u16* hout = (t&1) ? hs0 : hs1;

    // ---- stage h tile: 8 coherent 16B loads/thread -> swizzled LDS,
    //      ds_writes interleaved with counted vmcnt ----
    {
      const u16* hrow = hin + (size_t)(r0+srow)*1024;
      s16x8 v[8];
      #pragma unroll
      for(int kc=0;kc<8;kc++) v[kc] = gload16_coh(hrow + (kc*16+sc16)*8);
      asm volatile("s_waitcnt vmcnt(4)" ::: "memory");
      #pragma unroll
      for(int kc=0;kc<4;kc++){
        int chunk = kc*16+sc16;
        *(s16x8*)&As[chunk*256 + ((srow ^ (chunk&7))<<3)] = v[kc];
      }
      asm volatile("s_waitcnt vmcnt(0)" ::: "memory");
      #pragma unroll
      for(int kc=4;kc<8;kc++){
        int chunk = kc*16+sc16;
        *(s16x8*)&As[chunk*256 + ((srow ^ (chunk&7))<<3)] = v[kc];
      }
    }
    __syncthreads();   // tile staged

    // ---- recurrent GEMM: this wave's K-half, 64 MFMA, B from registers ----
    f32x4 acc[2][2];
    #pragma unroll
    for(int m=0;m<2;m++)
      #pragma unroll
      for(int n=0;n<2;n++) acc[m][n]=(f32x4){0.f,0.f,0.f,0.f};
    #pragma unroll
    for(int kk=0;kk<16;kk++){
      int c0 = (kg*16 + kk)*4 + hi;                 // 16B chunk 0..127
      s16x8 a0 = *(const s16x8*)&As[c0*256 + ((l15      ^ (c0&7))<<3)];
      s16x8 a1 = *(const s16x8*)&As[c0*256 + (((16+l15) ^ (c0&7))<<3)];
      acc[0][0] = MF(a0, breg[0][kk], acc[0][0]);
      acc[0][1] = MF(a0, breg[1][kk], acc[0][1]);
      acc[1][0] = MF(a1, breg[0][kk], acc[1][0]);
      acc[1][1] = MF(a1, breg[1][kk], acc[1][1]);
    }
    // no barrier needed: zpart is a separate LDS region

    // ---- K-half partial exchange: zpart[gate][kg][row][33] ----
    #pragma unroll
    for(int m=0;m<2;m++)
      #pragma unroll
      for(int n=0;n<2;n++)
        #pragma unroll
        for(int j=0;j<4;j++){
          int row = m*16 + hi*4 + j;
          zpart[((gate*2+kg)*32 + row)*33 + n*16 + l15] = acc[m][n][j];
        }
    __syncthreads();

    // ---- epilogue: sum K-halves, gates, state update; h stores first ----
    float nhv[2];
    #pragma unroll
    for(int e=0;e<2;e++){
      int row = e*16 + erow;
      float zi  = zr[0][e] + zpart[((0)*32+row)*33 + ecol] + zpart[((1)*32+row)*33 + ecol];
      float zf_ = zr[1][e] + zpart[((2)*32+row)*33 + ecol] + zpart[((3)*32+row)*33 + ecol];
      float zg  = zr[2][e] + zpart[((4)*32+row)*33 + ecol] + zpart[((5)*32+row)*33 + ecol];
      float zo  = zr[3][e] + zpart[((6)*32+row)*33 + ecol] + zpart[((7)*32+row)*33 + ecol];
      bool m_ = mm[e]!=0, d_ = md[e]!=0;
      float co = m_ ? c1r[e] : c2r[e];
      float nc = sigf(zf_)*co + sigf(zi)*tanh2(zg);
      float nhx = sigf(zo)*tanh2(nc);
      nhv[e] = nhx;
      float n1c = m_?nc:c1r[e], n2c = m_?c2r[e]:nc;
      float n1h = m_?nhx:h1r[e], n2h = m_?h2r[e]:nhx;
      if(d_){ n1c=0.f; n2c=0.f; n1h=0.f; n2h=0.f; }
      c1r[e]=n1c; c2r[e]=n2c; h1r[e]=n1h; h2r[e]=n2h;
      if(t<127)
        st_u16_coh(&hout[(size_t)(r0+row)*1024 + j0 + ecol], f2b(mm2[e] ? n1h : n2h));
    }
    asm volatile("s_waitcnt vmcnt(0)" ::: "memory");   // h at coherence point
    __syncthreads();
    if(t<127 && tid==0)
      __hip_atomic_fetch_add(flag, 1, __ATOMIC_RELAXED, __HIP_MEMORY_SCOPE_AGENT);

    // ---- out store off the critical path (drains during next spin) ----
    #pragma unroll
    for(int e=0;e<2;e++){
      int gb = t*256 + r0 + e*16 + erow;
      st_f32_coh(&out[(size_t)gb*1024 + j0 + ecol], nhv[e]);
    }
  }
}

// ---------------- host ----------------
extern "C" void kernel_launch(void* const* d_in, const int* in_sizes, int n_in,
                              void* d_out, int out_size, void* d_ws, size_t ws_size,
                              hipStream_t stream){
  const float* x   = (const float*)d_in[0];
  const float* c1i = (const float*)d_in[1];
  const float* h1i = (const float*)d_in[2];
  const float* c2i = (const float*)d_in[3];
  const float* h2i = (const float*)d_in[4];
  const float* Wi  = (const float*)d_in[5];
  const float* Wh  = (const float*)d_in[6];
  const float* bias= (const float*)d_in[7];
  const void* done_raw = d_in[8];
  const void* main_raw = d_in[9];
  float* out = (float*)d_out;

  char* ws = (char*)d_ws;
  size_t off=0;
  auto alloc=[&](size_t sz)->char*{ char* p = ws+off; off += (sz+255)&~(size_t)255; return p; };

  u16* xb   = (u16*)alloc(33554432ull*2);        // x as bf16 [32768][1024]
  u16* WiT  = (u16*)alloc(4096ull*1024*2);       // Wi^T bf16 [4096][1024]
  u16* WhT  = (u16*)alloc(4096ull*1024*2);       // Wh^T bf16 [4096][1024]
  u16* hs0  = (u16*)alloc(262144ull*2);
  u16* hs1  = (u16*)alloc(262144ull*2);
  u8* dmask = (u8*)alloc(32768);
  u8* mmask = (u8*)alloc(32768);
  int* flag = (int*)alloc(256);
  int* ready= (int*)alloc(1024);
  u16* Zx   = (u16*)alloc(268435456ull);         // Zx f16 [32768][4096] -- L3-resident

  detect_mask_mode<<<1,256,0,stream>>>((const u8*)done_raw, 32768, flag);
  convert_masks<<<64,256,0,stream>>>(done_raw, main_raw, dmask, mmask, 32768, flag);
  cvt_f32_bf16<<<32768,256,0,stream>>>(x, xb, 8388608);
  transpose_to_bf16<<<dim3(64,16),256,0,stream>>>(Wi, WiT, 1024, 4096);
  transpose_to_bf16<<<dim3(64,16),256,0,stream>>>(Wh, WhT, 1024, 4096);
  init_hsel<<<1024,256,0,stream>>>(h1i, h2i, mmask, hs0);
  zero_flags<<<1,256,0,stream>>>(ready, 256);

  gemm_zx<<<2048,512,0,stream>>>(xb, WiT, bias, Zx);

  lstm_persist<<<256,512,0,stream>>>(Zx,WhT,hs0,hs1,c1i,h1i,c2i,h2i,dmask,mmask,out,ready);
}

// Round 16
// 1036.442 us; speedup vs baseline: 1.0236x; 1.0167x over previous
//
#include <hip/hip_runtime.h>
#include <cstdint>
#include <cstddef>

typedef unsigned short u16;
typedef unsigned char u8;
typedef unsigned int u32;

typedef short s16x8 __attribute__((ext_vector_type(8)));
typedef float f32x4 __attribute__((ext_vector_type(4)));

#define MF(a,b,c) __builtin_amdgcn_mfma_f32_16x16x32_bf16((a),(b),(c),0,0,0)

// ---------------- helpers ----------------
__device__ __forceinline__ float b2f(u16 h){ u32 u = ((u32)h)<<16; float f; __builtin_memcpy(&f,&u,4); return f; }
__device__ __forceinline__ u16 f2b(float x){ u32 u; __builtin_memcpy(&u,&x,4); u += 0x7fffu + ((u>>16)&1u); return (u16)(u>>16); }
__device__ __forceinline__ u16 f2h(float x){ _Float16 h = (_Float16)x; u16 u; __builtin_memcpy(&u,&h,2); return u; }
__device__ __forceinline__ float h2f(u16 v){ _Float16 h; __builtin_memcpy(&h,&v,2); return (float)h; }
__device__ __forceinline__ float sigf(float x){ return __builtin_amdgcn_rcpf(1.f+__expf(-x)); }
__device__ __forceinline__ float tanh2(float x){
  float ax=fabsf(x); float e=__expf(-2.f*ax);
  float r=(1.f-e)*__builtin_amdgcn_rcpf(1.f+e);
  return x<0.f? -r : r;
}

typedef __attribute__((address_space(1))) const void gvoid_t;
typedef __attribute__((address_space(3))) void lvoid_t;
__device__ __forceinline__ void gl_lds16(const u16* src, u16* dst){
  __builtin_amdgcn_global_load_lds((gvoid_t*)src, (lvoid_t*)dst, 16, 0, 0);
}

// coherent write-through store (no L2 dirtying; visible at coherence point)
__device__ __forceinline__ void st_u16_coh(u16* p, u16 v){
  asm volatile("global_store_short %0, %1, off sc0 sc1" :: "v"(p), "v"((u32)v) : "memory");
}
__device__ __forceinline__ void st_f32_coh(float* p, float v){
  asm volatile("global_store_dword %0, %1, off sc0 sc1" :: "v"(p), "v"(v) : "memory");
}
// pinned (non-rematerializable) 16B load
__device__ __forceinline__ s16x8 gload16(const u16* p){
  s16x8 r;
  asm volatile("global_load_dwordx4 %0, %1, off" : "=v"(r) : "v"(p) : "memory");
  return r;
}
// coherent 16B load: reads at coherence point (never stale)
__device__ __forceinline__ s16x8 gload16_coh(const u16* p){
  s16x8 r;
  asm volatile("global_load_dwordx4 %0, %1, off sc0 sc1" : "=v"(r) : "v"(p) : "memory");
  return r;
}

// ---------------- mask dtype detection + canonicalization ----------------
__global__ void detect_mask_mode(const u8* raw, int n, int* flag){
  __shared__ int cnt;
  int tid = threadIdx.x;
  if(tid==0) cnt=0;
  __syncthreads();
  int c=0;
  for(int i=tid;i<n;i+=blockDim.x) c += (raw[i]!=0);
  atomicAdd(&cnt, c);
  __syncthreads();
  if(tid==0) *flag = (cnt > (n>>2)) ? 1 : 0;  // 1 => byte-per-element layout
}

__global__ void convert_masks(const void* done_raw, const void* main_raw, u8* done_u8, u8* main_u8, int n, const int* flag){
  int mode = *flag;
  for(int i = blockIdx.x*blockDim.x + threadIdx.x; i<n; i += gridDim.x*blockDim.x){
    u8 d, m;
    if(mode){ d = ((const u8*)done_raw)[i]!=0; m = ((const u8*)main_raw)[i]!=0; }
    else    { d = ((const int*)done_raw)[i]!=0; m = ((const int*)main_raw)[i]!=0; }
    done_u8[i]=d; main_u8[i]=m;
  }
}

__global__ void zero_flags(int* p, int n){
  int i = blockIdx.x*blockDim.x + threadIdx.x;
  if(i<n) p[i]=0;
}

// ---------------- conversions ----------------
__global__ void cvt_f32_bf16(const float* __restrict__ in, u16* __restrict__ out, int n4){
  int i = blockIdx.x*blockDim.x + threadIdx.x;
  if(i < n4){
    float4 v = ((const float4*)in)[i];
    ushort4 o;
    o.x=f2b(v.x); o.y=f2b(v.y); o.z=f2b(v.z); o.w=f2b(v.w);
    ((ushort4*)out)[i]=o;
  }
}

// in [R][C] f32  ->  out [C][R] bf16
__global__ void transpose_to_bf16(const float* __restrict__ in, u16* __restrict__ out, int R, int C){
  __shared__ float tile[64][65];
  int c0 = blockIdx.x*64, r0 = blockIdx.y*64;
  int tx = threadIdx.x & 63, ty = threadIdx.x >> 6;   // 256 threads
  for(int i=ty;i<64;i+=4) tile[i][tx] = in[(size_t)(r0+i)*C + c0 + tx];
  __syncthreads();
  for(int i=ty;i<64;i+=4) out[(size_t)(c0+i)*R + r0 + tx] = f2b(tile[tx][i]);
}

__global__ void init_hsel(const float* __restrict__ h1in, const float* __restrict__ h2in,
                          const u8* __restrict__ mmain, u16* __restrict__ hsel0){
  int i = blockIdx.x*blockDim.x + threadIdx.x;
  if(i < 256*1024){
    int row = i >> 10;
    hsel0[i] = f2b(mmain[row] ? h1in[i] : h2in[i]);
  }
}

// ---------------- phase 1: Zx = x @ Wi + b  (R6-exact m97-style, f16 out) ----------------
__global__ __launch_bounds__(256) void gemm_zx(const u16* __restrict__ A, const u16* __restrict__ Bt,
                                               const float* __restrict__ bias, u16* __restrict__ C){
  __shared__ u16 As[128*32];
  __shared__ u16 Bs[128*32];
  const int nbx = 32;                // N/128
  const int nwg = 8192;              // (M/128)*(N/128), divisible by 8
  int gid = blockIdx.x;
  int per = nwg>>3;
  int g2 = (gid&7)*per + (gid>>3);   // XCD-contiguous remap (bijective: nwg%8==0)
  int tpg = 8*nbx;                   // 8-row supergroup x all cols
  int grp = g2/tpg, w = g2%tpg;
  int brow = grp*8 + (w & 7);
  int bcol = w >> 3;
  int row0 = brow<<7, col0 = bcol<<7;

  int tid=threadIdx.x, wid=tid>>6, lane=tid&63;
  int l15=lane&15, hi=lane>>4;
  int wm=(wid>>1)<<6, wn=(wid&1)<<6;

  f32x4 acc[4][4];
  #pragma unroll
  for(int m=0;m<4;m++)
    #pragma unroll
    for(int n=0;n<4;n++) acc[m][n]=(f32x4){0.f,0.f,0.f,0.f};

  for(int k0=0;k0<1024;k0+=32){
    __syncthreads();
    #pragma unroll
    for(int q=0;q<2;q++){
      int cb=q*256+wid*64;
      int ch=cb+lane;
      gl_lds16(A + (size_t)(row0+(ch>>2))*1024 + k0 + (ch&3)*8, &As[cb*8]);
    }
    #pragma unroll
    for(int q=0;q<2;q++){
      int cb=q*256+wid*64;
      int ch=cb+lane;
      gl_lds16(Bt + (size_t)(col0+(ch>>2))*1024 + k0 + (ch&3)*8, &Bs[cb*8]);
    }
    __syncthreads();
    s16x8 a[4], b[4];
    #pragma unroll
    for(int m=0;m<4;m++) a[m] = *(const s16x8*)&As[(wm+m*16+l15)*32 + hi*8];
    #pragma unroll
    for(int n=0;n<4;n++) b[n] = *(const s16x8*)&Bs[(wn+n*16+l15)*32 + hi*8];
    #pragma unroll
    for(int m=0;m<4;m++)
      #pragma unroll
      for(int n=0;n<4;n++)
        acc[m][n] = MF(a[m],b[n],acc[m][n]);
  }
  #pragma unroll
  for(int m=0;m<4;m++){
    #pragma unroll
    for(int n=0;n<4;n++){
      int c = col0+wn+n*16+l15;
      float bv = bias[c];
      #pragma unroll
      for(int j=0;j<4;j++){
        int r = row0+wm+m*16+hi*4+j;
        C[(size_t)r*4096+c] = f2h(acc[m][n][j] + bv);
      }
    }
  }
}

// ---------------- phase 2: persistent recurrent kernel (R12-exact) ----------------
__global__ __launch_bounds__(512) __attribute__((amdgpu_waves_per_eu(2,2)))
void lstm_persist(
    const u16* __restrict__ Zx, const u16* __restrict__ Wht,
    u16* __restrict__ hs0, u16* __restrict__ hs1,
    const float* __restrict__ c1i, const float* __restrict__ h1i,
    const float* __restrict__ c2i, const float* __restrict__ h2i,
    const u8* __restrict__ mdone, const u8* __restrict__ mmain,
    float* __restrict__ out, int* __restrict__ ready)
{
  __shared__ u16 As[32768];            // 64 KB: 128 chunks x [32 rows x 16B], XOR-swizzled
  __shared__ float zpart[4*2*32*33];   // 33 KB: [gate][kg][row][33] partial sums

  const int bid = blockIdx.x;
  const int rg = bid & 7, jg = bid >> 3;
  const int r0 = rg << 5, j0 = jg << 5;
  const int tid = threadIdx.x, wid = tid >> 6, lane = tid & 63;
  const int l15 = lane & 15, hi = lane >> 4;
  const int gate = wid >> 1, kg = wid & 1;
  const int srow = tid >> 4, sc16 = tid & 15;   // staging: row 0..31, col16 0..15
  const int erow = tid >> 5, ecol = tid & 31;   // epilogue: rows, 32 cols

  // ---- Wh^T fragments: this wave's (gate, K-half) x 32 cols: 128 VGPRs ----
  s16x8 breg[2][16];
  {
    #pragma unroll
    for(int n=0;n<2;n++){
      const u16* wp = Wht + ((size_t)(gate*1024 + j0 + n*16 + l15))*1024 + kg*512 + hi*8;
      #pragma unroll
      for(int kk=0;kk<16;kk++) breg[n][kk] = gload16(wp + kk*32);
    }
    asm volatile("s_waitcnt vmcnt(0)" ::: "memory");
    __builtin_amdgcn_sched_barrier(0);
  }

  // ---- states into registers (thread-stationary across all 128 steps) ----
  float c1r[2],c2r[2],h1r[2],h2r[2];
  #pragma unroll
  for(int e=0;e<2;e++){
    size_t sidx = (size_t)(r0 + e*16 + erow)*1024 + j0 + ecol;
    c1r[e]=c1i[sidx]; c2r[e]=c2i[sidx]; h1r[e]=h1i[sidx]; h2r[e]=h2i[sidx];
  }

  int* flag = ready + rg*32;    // 128B-spaced per-rg counters

  for(int t=0;t<128;t++){
    // ---- prefetch step-local immutable inputs (f16 Zx is L3-resident) ----
    float zr[4][2]; u8 md[2], mm[2], mm2[2];
    #pragma unroll
    for(int e=0;e<2;e++){
      int gb = t*256 + r0 + e*16 + erow;
      size_t base = (size_t)gb*4096 + j0 + ecol;
      #pragma unroll
      for(int g=0; g<4; g++)
        zr[g][e] = h2f(Zx[base + g*1024]);
      md[e]=mdone[gb]; mm[e]=mmain[gb];
      mm2[e] = (t<127) ? mmain[gb+256] : (u8)0;
    }

    // ---- chain wait (single spinner; others park at the barrier) ----
    if(t>0 && tid==0){
      while(__hip_atomic_load(flag, __ATOMIC_RELAXED, __HIP_MEMORY_SCOPE_AGENT) < 32*t)
        __builtin_amdgcn_s_sleep(1);
    }
    __syncthreads();
    __builtin_amdgcn_sched_barrier(0);

    const u16* hin = (t&1) ? hs1 : hs0;
    u16* hout = (t&1) ? hs0 : hs1;

    // ---- stage h tile: 8 coherent 16B loads/thread -> swizzled LDS,
    //      ds_writes interleaved with counted vmcnt ----
    {
      const u16* hrow = hin + (size_t)(r0+srow)*1024;
      s16x8 v[8];
      #pragma unroll
      for(int kc=0;kc<8;kc++) v[kc] = gload16_coh(hrow + (kc*16+sc16)*8);
      asm volatile("s_waitcnt vmcnt(4)" ::: "memory");
      #pragma unroll
      for(int kc=0;kc<4;kc++){
        int chunk = kc*16+sc16;
        *(s16x8*)&As[chunk*256 + ((srow ^ (chunk&7))<<3)] = v[kc];
      }
      asm volatile("s_waitcnt vmcnt(0)" ::: "memory");
      #pragma unroll
      for(int kc=4;kc<8;kc++){
        int chunk = kc*16+sc16;
        *(s16x8*)&As[chunk*256 + ((srow ^ (chunk&7))<<3)] = v[kc];
      }
    }
    __syncthreads();   // tile staged

    // ---- recurrent GEMM: this wave's K-half, 64 MFMA, B from registers ----
    f32x4 acc[2][2];
    #pragma unroll
    for(int m=0;m<2;m++)
      #pragma unroll
      for(int n=0;n<2;n++) acc[m][n]=(f32x4){0.f,0.f,0.f,0.f};
    #pragma unroll
    for(int kk=0;kk<16;kk++){
      int c0 = (kg*16 + kk)*4 + hi;                 // 16B chunk 0..127
      s16x8 a0 = *(const s16x8*)&As[c0*256 + ((l15      ^ (c0&7))<<3)];
      s16x8 a1 = *(const s16x8*)&As[c0*256 + (((16+l15) ^ (c0&7))<<3)];
      acc[0][0] = MF(a0, breg[0][kk], acc[0][0]);
      acc[0][1] = MF(a0, breg[1][kk], acc[0][1]);
      acc[1][0] = MF(a1, breg[0][kk], acc[1][0]);
      acc[1][1] = MF(a1, breg[1][kk], acc[1][1]);
    }
    // no barrier needed: zpart is a separate LDS region

    // ---- K-half partial exchange: zpart[gate][kg][row][33] ----
    #pragma unroll
    for(int m=0;m<2;m++)
      #pragma unroll
      for(int n=0;n<2;n++)
        #pragma unroll
        for(int j=0;j<4;j++){
          int row = m*16 + hi*4 + j;
          zpart[((gate*2+kg)*32 + row)*33 + n*16 + l15] = acc[m][n][j];
        }
    __syncthreads();

    // ---- epilogue: sum K-halves, gates, state update; h stores first ----
    float nhv[2];
    #pragma unroll
    for(int e=0;e<2;e++){
      int row = e*16 + erow;
      float zi  = zr[0][e] + zpart[((0)*32+row)*33 + ecol] + zpart[((1)*32+row)*33 + ecol];
      float zf_ = zr[1][e] + zpart[((2)*32+row)*33 + ecol] + zpart[((3)*32+row)*33 + ecol];
      float zg  = zr[2][e] + zpart[((4)*32+row)*33 + ecol] + zpart[((5)*32+row)*33 + ecol];
      float zo  = zr[3][e] + zpart[((6)*32+row)*33 + ecol] + zpart[((7)*32+row)*33 + ecol];
      bool m_ = mm[e]!=0, d_ = md[e]!=0;
      float co = m_ ? c1r[e] : c2r[e];
      float nc = sigf(zf_)*co + sigf(zi)*tanh2(zg);
      float nhx = sigf(zo)*tanh2(nc);
      nhv[e] = nhx;
      float n1c = m_?nc:c1r[e], n2c = m_?c2r[e]:nc;
      float n1h = m_?nhx:h1r[e], n2h = m_?h2r[e]:nhx;
      if(d_){ n1c=0.f; n2c=0.f; n1h=0.f; n2h=0.f; }
      c1r[e]=n1c; c2r[e]=n2c; h1r[e]=n1h; h2r[e]=n2h;
      if(t<127)
        st_u16_coh(&hout[(size_t)(r0+row)*1024 + j0 + ecol], f2b(mm2[e] ? n1h : n2h));
    }
    asm volatile("s_waitcnt vmcnt(0)" ::: "memory");   // h at coherence point
    __syncthreads();
    if(t<127 && tid==0)
      __hip_atomic_fetch_add(flag, 1, __ATOMIC_RELAXED, __HIP_MEMORY_SCOPE_AGENT);

    // ---- out store off the critical path (drains during next spin) ----
    #pragma unroll
    for(int e=0;e<2;e++){
      int gb = t*256 + r0 + e*16 + erow;
      st_f32_coh(&out[(size_t)gb*1024 + j0 + ecol], nhv[e]);
    }
  }
}

// ---------------- host ----------------
extern "C" void kernel_launch(void* const* d_in, const int* in_sizes, int n_in,
                              void* d_out, int out_size, void* d_ws, size_t ws_size,
                              hipStream_t stream){
  const float* x   = (const float*)d_in[0];
  const float* c1i = (const float*)d_in[1];
  const float* h1i = (const float*)d_in[2];
  const float* c2i = (const float*)d_in[3];
  const float* h2i = (const float*)d_in[4];
  const float* Wi  = (const float*)d_in[5];
  const float* Wh  = (const float*)d_in[6];
  const float* bias= (const float*)d_in[7];
  const void* done_raw = d_in[8];
  const void* main_raw = d_in[9];
  float* out = (float*)d_out;

  char* ws = (char*)d_ws;
  size_t off=0;
  auto alloc=[&](size_t sz)->char*{ char* p = ws+off; off += (sz+255)&~(size_t)255; return p; };

  u16* xb   = (u16*)alloc(33554432ull*2);        // x as bf16 [32768][1024]
  u16* WiT  = (u16*)alloc(4096ull*1024*2);       // Wi^T bf16 [4096][1024]
  u16* WhT  = (u16*)alloc(4096ull*1024*2);       // Wh^T bf16 [4096][1024]
  u16* hs0  = (u16*)alloc(262144ull*2);
  u16* hs1  = (u16*)alloc(262144ull*2);
  u8* dmask = (u8*)alloc(32768);
  u8* mmask = (u8*)alloc(32768);
  int* flag = (int*)alloc(256);
  int* ready= (int*)alloc(1024);
  u16* Zx   = (u16*)alloc(268435456ull);         // Zx f16 [32768][4096] -- L3-resident

  detect_mask_mode<<<1,256,0,stream>>>((const u8*)done_raw, 32768, flag);
  convert_masks<<<64,256,0,stream>>>(done_raw, main_raw, dmask, mmask, 32768, flag);
  cvt_f32_bf16<<<32768,256,0,stream>>>(x, xb, 8388608);
  transpose_to_bf16<<<dim3(64,16),256,0,stream>>>(Wi, WiT, 1024, 4096);
  transpose_to_bf16<<<dim3(64,16),256,0,stream>>>(Wh, WhT, 1024, 4096);
  init_hsel<<<1024,256,0,stream>>>(h1i, h2i, mmask, hs0);
  zero_flags<<<1,256,0,stream>>>(ready, 256);

  gemm_zx<<<8192,256,0,stream>>>(xb, WiT, bias, Zx);

  lstm_persist<<<256,512,0,stream>>>(Zx,WhT,hs0,hs1,c1i,h1i,c2i,h2i,dmask,mmask,out,ready);
}

// Round 17
// 1032.367 us; speedup vs baseline: 1.0276x; 1.0039x over previous
//
#include <hip/hip_runtime.h>
#include <cstdint>
#include <cstddef>

typedef unsigned short u16;
typedef unsigned char u8;
typedef unsigned int u32;

typedef short s16x8 __attribute__((ext_vector_type(8)));
typedef float f32x4 __attribute__((ext_vector_type(4)));

#define MF(a,b,c) __builtin_amdgcn_mfma_f32_16x16x32_bf16((a),(b),(c),0,0,0)

// ---------------- helpers ----------------
__device__ __forceinline__ float b2f(u16 h){ u32 u = ((u32)h)<<16; float f; __builtin_memcpy(&f,&u,4); return f; }
__device__ __forceinline__ u16 f2b(float x){ u32 u; __builtin_memcpy(&u,&x,4); u += 0x7fffu + ((u>>16)&1u); return (u16)(u>>16); }
__device__ __forceinline__ u16 f2h(float x){ _Float16 h = (_Float16)x; u16 u; __builtin_memcpy(&u,&h,2); return u; }
__device__ __forceinline__ float h2f(u16 v){ _Float16 h; __builtin_memcpy(&h,&v,2); return (float)h; }
__device__ __forceinline__ float sigf(float x){ return __builtin_amdgcn_rcpf(1.f+__expf(-x)); }
__device__ __forceinline__ float tanh2(float x){
  float ax=fabsf(x); float e=__expf(-2.f*ax);
  float r=(1.f-e)*__builtin_amdgcn_rcpf(1.f+e);
  return x<0.f? -r : r;
}

typedef __attribute__((address_space(1))) const void gvoid_t;
typedef __attribute__((address_space(3))) void lvoid_t;
__device__ __forceinline__ void gl_lds16(const u16* src, u16* dst){
  __builtin_amdgcn_global_load_lds((gvoid_t*)src, (lvoid_t*)dst, 16, 0, 0);
}

// coherent write-through store (no L2 dirtying; visible at coherence point)
__device__ __forceinline__ void st_u16_coh(u16* p, u16 v){
  asm volatile("global_store_short %0, %1, off sc0 sc1" :: "v"(p), "v"((u32)v) : "memory");
}
__device__ __forceinline__ void st_f32_coh(float* p, float v){
  asm volatile("global_store_dword %0, %1, off sc0 sc1" :: "v"(p), "v"(v) : "memory");
}
__device__ __forceinline__ void st_i32_coh(int* p, int v){
  asm volatile("global_store_dword %0, %1, off sc0 sc1" :: "v"(p), "v"(v) : "memory");
}
// coherent i32 load (point read; explicit wait inside)
__device__ __forceinline__ int ld_i32_coh(const int* p){
  int r;
  asm volatile("global_load_dword %0, %1, off sc0 sc1" : "=v"(r) : "v"(p) : "memory");
  asm volatile("s_waitcnt vmcnt(0)" ::: "memory");
  return r;
}
// pinned (non-rematerializable) 16B load
__device__ __forceinline__ s16x8 gload16(const u16* p){
  s16x8 r;
  asm volatile("global_load_dwordx4 %0, %1, off" : "=v"(r) : "v"(p) : "memory");
  return r;
}
// coherent 16B load: reads at coherence point (never stale)
__device__ __forceinline__ s16x8 gload16_coh(const u16* p){
  s16x8 r;
  asm volatile("global_load_dwordx4 %0, %1, off sc0 sc1" : "=v"(r) : "v"(p) : "memory");
  return r;
}

// ---------------- mask dtype detection + canonicalization ----------------
__global__ void detect_mask_mode(const u8* raw, int n, int* flag){
  __shared__ int cnt;
  int tid = threadIdx.x;
  if(tid==0) cnt=0;
  __syncthreads();
  int c=0;
  for(int i=tid;i<n;i+=blockDim.x) c += (raw[i]!=0);
  atomicAdd(&cnt, c);
  __syncthreads();
  if(tid==0) *flag = (cnt > (n>>2)) ? 1 : 0;  // 1 => byte-per-element layout
}

__global__ void convert_masks(const void* done_raw, const void* main_raw, u8* done_u8, u8* main_u8, int n, const int* flag){
  int mode = *flag;
  for(int i = blockIdx.x*blockDim.x + threadIdx.x; i<n; i += gridDim.x*blockDim.x){
    u8 d, m;
    if(mode){ d = ((const u8*)done_raw)[i]!=0; m = ((const u8*)main_raw)[i]!=0; }
    else    { d = ((const int*)done_raw)[i]!=0; m = ((const int*)main_raw)[i]!=0; }
    done_u8[i]=d; main_u8[i]=m;
  }
}

__global__ void zero_flags(int* p, int n){
  int i = blockIdx.x*blockDim.x + threadIdx.x;
  if(i<n) p[i]=0;
}

// ---------------- conversions ----------------
__global__ void cvt_f32_bf16(const float* __restrict__ in, u16* __restrict__ out, int n4){
  int i = blockIdx.x*blockDim.x + threadIdx.x;
  if(i < n4){
    float4 v = ((const float4*)in)[i];
    ushort4 o;
    o.x=f2b(v.x); o.y=f2b(v.y); o.z=f2b(v.z); o.w=f2b(v.w);
    ((ushort4*)out)[i]=o;
  }
}

// in [R][C] f32  ->  out [C][R] bf16
__global__ void transpose_to_bf16(const float* __restrict__ in, u16* __restrict__ out, int R, int C){
  __shared__ float tile[64][65];
  int c0 = blockIdx.x*64, r0 = blockIdx.y*64;
  int tx = threadIdx.x & 63, ty = threadIdx.x >> 6;   // 256 threads
  for(int i=ty;i<64;i+=4) tile[i][tx] = in[(size_t)(r0+i)*C + c0 + tx];
  __syncthreads();
  for(int i=ty;i<64;i+=4) out[(size_t)(c0+i)*R + r0 + tx] = f2b(tile[tx][i]);
}

__global__ void init_hsel(const float* __restrict__ h1in, const float* __restrict__ h2in,
                          const u8* __restrict__ mmain, u16* __restrict__ hsel0){
  int i = blockIdx.x*blockDim.x + threadIdx.x;
  if(i < 256*1024){
    int row = i >> 10;
    hsel0[i] = f2b(mmain[row] ? h1in[i] : h2in[i]);
  }
}

// ---------------- phase 1: Zx = x @ Wi + b  (R6-exact m97-style, f16 out) ----------------
__global__ __launch_bounds__(256) void gemm_zx(const u16* __restrict__ A, const u16* __restrict__ Bt,
                                               const float* __restrict__ bias, u16* __restrict__ C){
  __shared__ u16 As[128*32];
  __shared__ u16 Bs[128*32];
  const int nbx = 32;                // N/128
  const int nwg = 8192;              // (M/128)*(N/128), divisible by 8
  int gid = blockIdx.x;
  int per = nwg>>3;
  int g2 = (gid&7)*per + (gid>>3);   // XCD-contiguous remap (bijective: nwg%8==0)
  int tpg = 8*nbx;                   // 8-row supergroup x all cols
  int grp = g2/tpg, w = g2%tpg;
  int brow = grp*8 + (w & 7);
  int bcol = w >> 3;
  int row0 = brow<<7, col0 = bcol<<7;

  int tid=threadIdx.x, wid=tid>>6, lane=tid&63;
  int l15=lane&15, hi=lane>>4;
  int wm=(wid>>1)<<6, wn=(wid&1)<<6;

  f32x4 acc[4][4];
  #pragma unroll
  for(int m=0;m<4;m++)
    #pragma unroll
    for(int n=0;n<4;n++) acc[m][n]=(f32x4){0.f,0.f,0.f,0.f};

  for(int k0=0;k0<1024;k0+=32){
    __syncthreads();
    #pragma unroll
    for(int q=0;q<2;q++){
      int cb=q*256+wid*64;
      int ch=cb+lane;
      gl_lds16(A + (size_t)(row0+(ch>>2))*1024 + k0 + (ch&3)*8, &As[cb*8]);
    }
    #pragma unroll
    for(int q=0;q<2;q++){
      int cb=q*256+wid*64;
      int ch=cb+lane;
      gl_lds16(Bt + (size_t)(col0+(ch>>2))*1024 + k0 + (ch&3)*8, &Bs[cb*8]);
    }
    __syncthreads();
    s16x8 a[4], b[4];
    #pragma unroll
    for(int m=0;m<4;m++) a[m] = *(const s16x8*)&As[(wm+m*16+l15)*32 + hi*8];
    #pragma unroll
    for(int n=0;n<4;n++) b[n] = *(const s16x8*)&Bs[(wn+n*16+l15)*32 + hi*8];
    #pragma unroll
    for(int m=0;m<4;m++)
      #pragma unroll
      for(int n=0;n<4;n++)
        acc[m][n] = MF(a[m],b[n],acc[m][n]);
  }
  #pragma unroll
  for(int m=0;m<4;m++){
    #pragma unroll
    for(int n=0;n<4;n++){
      int c = col0+wn+n*16+l15;
      float bv = bias[c];
      #pragma unroll
      for(int j=0;j<4;j++){
        int r = row0+wm+m*16+hi*4+j;
        C[(size_t)r*4096+c] = f2h(acc[m][n][j] + bv);
      }
    }
  }
}

// ---------------- phase 2: persistent recurrent kernel ----------------
// R12 champion with atomic-free chain sync:
//  release: block (rg,jg) writes epoch[rg*32+jg] = t+1 (sc0sc1 store, no RMW)
//  wait: wave 0's 32 lanes coalesced-load the chain's epoch line, __all(e>=t)
__global__ __launch_bounds__(512) __attribute__((amdgpu_waves_per_eu(2,2)))
void lstm_persist(
    const u16* __restrict__ Zx, const u16* __restrict__ Wht,
    u16* __restrict__ hs0, u16* __restrict__ hs1,
    const float* __restrict__ c1i, const float* __restrict__ h1i,
    const float* __restrict__ c2i, const float* __restrict__ h2i,
    const u8* __restrict__ mdone, const u8* __restrict__ mmain,
    float* __restrict__ out, int* __restrict__ ready)
{
  __shared__ u16 As[32768];            // 64 KB: 128 chunks x [32 rows x 16B], XOR-swizzled
  __shared__ float zpart[4*2*32*33];   // 33 KB: [gate][kg][row][33] partial sums

  const int bid = blockIdx.x;
  const int rg = bid & 7, jg = bid >> 3;
  const int r0 = rg << 5, j0 = jg << 5;
  const int tid = threadIdx.x, wid = tid >> 6, lane = tid & 63;
  const int l15 = lane & 15, hi = lane >> 4;
  const int gate = wid >> 1, kg = wid & 1;
  const int srow = tid >> 4, sc16 = tid & 15;   // staging: row 0..31, col16 0..15
  const int erow = tid >> 5, ecol = tid & 31;   // epilogue: rows, 32 cols

  // ---- Wh^T fragments: this wave's (gate, K-half) x 32 cols: 128 VGPRs ----
  s16x8 breg[2][16];
  {
    #pragma unroll
    for(int n=0;n<2;n++){
      const u16* wp = Wht + ((size_t)(gate*1024 + j0 + n*16 + l15))*1024 + kg*512 + hi*8;
      #pragma unroll
      for(int kk=0;kk<16;kk++) breg[n][kk] = gload16(wp + kk*32);
    }
    asm volatile("s_waitcnt vmcnt(0)" ::: "memory");
    __builtin_amdgcn_sched_barrier(0);
  }

  // ---- states into registers (thread-stationary across all 128 steps) ----
  float c1r[2],c2r[2],h1r[2],h2r[2];
  #pragma unroll
  for(int e=0;e<2;e++){
    size_t sidx = (size_t)(r0 + e*16 + erow)*1024 + j0 + ecol;
    c1r[e]=c1i[sidx]; c2r[e]=c2i[sidx]; h1r[e]=h1i[sidx]; h2r[e]=h2i[sidx];
  }

  int* epoch = ready + rg*32;   // 128B line per rg: one int per jg block

  for(int t=0;t<128;t++){
    // ---- prefetch step-local immutable inputs (f16 Zx is L3-resident) ----
    float zr[4][2]; u8 md[2], mm[2], mm2[2];
    #pragma unroll
    for(int e=0;e<2;e++){
      int gb = t*256 + r0 + e*16 + erow;
      size_t base = (size_t)gb*4096 + j0 + ecol;
      #pragma unroll
      for(int g=0; g<4; g++)
        zr[g][e] = h2f(Zx[base + g*1024]);
      md[e]=mdone[gb]; mm[e]=mmain[gb];
      mm2[e] = (t<127) ? mmain[gb+256] : (u8)0;
    }

    // ---- chain wait: wave 0, coalesced epoch-line poll ----
    if(t>0 && wid==0){
      const int* ep = epoch + (lane & 31);
      while(true){
        int e = ld_i32_coh(ep);
        if(__all(e >= t)) break;
        __builtin_amdgcn_s_sleep(1);
      }
    }
    __syncthreads();
    __builtin_amdgcn_sched_barrier(0);

    const u16* hin = (t&1) ? hs1 : hs0;
    u16* hout = (t&1) ? hs0 : hs1;

    // ---- stage h tile: 8 coherent 16B loads/thread -> swizzled LDS,
    //      ds_writes interleaved with counted vmcnt ----
    {
      const u16* hrow = hin + (size_t)(r0+srow)*1024;
      s16x8 v[8];
      #pragma unroll
      for(int kc=0;kc<8;kc++) v[kc] = gload16_coh(hrow + (kc*16+sc16)*8);
      asm volatile("s_waitcnt vmcnt(4)" ::: "memory");
      #pragma unroll
      for(int kc=0;kc<4;kc++){
        int chunk = kc*16+sc16;
        *(s16x8*)&As[chunk*256 + ((srow ^ (chunk&7))<<3)] = v[kc];
      }
      asm volatile("s_waitcnt vmcnt(0)" ::: "memory");
      #pragma unroll
      for(int kc=4;kc<8;kc++){
        int chunk = kc*16+sc16;
        *(s16x8*)&As[chunk*256 + ((srow ^ (chunk&7))<<3)] = v[kc];
      }
    }
    __syncthreads();   // tile staged

    // ---- recurrent GEMM: this wave's K-half, 64 MFMA, B from registers ----
    f32x4 acc[2][2];
    #pragma unroll
    for(int m=0;m<2;m++)
      #pragma unroll
      for(int n=0;n<2;n++) acc[m][n]=(f32x4){0.f,0.f,0.f,0.f};
    #pragma unroll
    for(int kk=0;kk<16;kk++){
      int c0 = (kg*16 + kk)*4 + hi;                 // 16B chunk 0..127
      s16x8 a0 = *(const s16x8*)&As[c0*256 + ((l15      ^ (c0&7))<<3)];
      s16x8 a1 = *(const s16x8*)&As[c0*256 + (((16+l15) ^ (c0&7))<<3)];
      acc[0][0] = MF(a0, breg[0][kk], acc[0][0]);
      acc[0][1] = MF(a0, breg[1][kk], acc[0][1]);
      acc[1][0] = MF(a1, breg[0][kk], acc[1][0]);
      acc[1][1] = MF(a1, breg[1][kk], acc[1][1]);
    }
    // no barrier needed: zpart is a separate LDS region

    // ---- K-half partial exchange: zpart[gate][kg][row][33] ----
    #pragma unroll
    for(int m=0;m<2;m++)
      #pragma unroll
      for(int n=0;n<2;n++)
        #pragma unroll
        for(int j=0;j<4;j++){
          int row = m*16 + hi*4 + j;
          zpart[((gate*2+kg)*32 + row)*33 + n*16 + l15] = acc[m][n][j];
        }
    __syncthreads();

    // ---- epilogue: sum K-halves, gates, state update; h stores first ----
    float nhv[2];
    #pragma unroll
    for(int e=0;e<2;e++){
      int row = e*16 + erow;
      float zi  = zr[0][e] + zpart[((0)*32+row)*33 + ecol] + zpart[((1)*32+row)*33 + ecol];
      float zf_ = zr[1][e] + zpart[((2)*32+row)*33 + ecol] + zpart[((3)*32+row)*33 + ecol];
      float zg  = zr[2][e] + zpart[((4)*32+row)*33 + ecol] + zpart[((5)*32+row)*33 + ecol];
      float zo  = zr[3][e] + zpart[((6)*32+row)*33 + ecol] + zpart[((7)*32+row)*33 + ecol];
      bool m_ = mm[e]!=0, d_ = md[e]!=0;
      float co = m_ ? c1r[e] : c2r[e];
      float nc = sigf(zf_)*co + sigf(zi)*tanh2(zg);
      float nhx = sigf(zo)*tanh2(nc);
      nhv[e] = nhx;
      float n1c = m_?nc:c1r[e], n2c = m_?c2r[e]:nc;
      float n1h = m_?nhx:h1r[e], n2h = m_?h2r[e]:nhx;
      if(d_){ n1c=0.f; n2c=0.f; n1h=0.f; n2h=0.f; }
      c1r[e]=n1c; c2r[e]=n2c; h1r[e]=n1h; h2r[e]=n2h;
      if(t<127)
        st_u16_coh(&hout[(size_t)(r0+row)*1024 + j0 + ecol], f2b(mm2[e] ? n1h : n2h));
    }
    asm volatile("s_waitcnt vmcnt(0)" ::: "memory");   // h at coherence point
    __syncthreads();
    if(t<127 && tid==0)
      st_i32_coh(epoch + jg, t+1);   // atomic-free release (own slot)

    // ---- out store off the critical path (drains during next spin) ----
    #pragma unroll
    for(int e=0;e<2;e++){
      int gb = t*256 + r0 + e*16 + erow;
      st_f32_coh(&out[(size_t)gb*1024 + j0 + ecol], nhv[e]);
    }
  }
}

// ---------------- host ----------------
extern "C" void kernel_launch(void* const* d_in, const int* in_sizes, int n_in,
                              void* d_out, int out_size, void* d_ws, size_t ws_size,
                              hipStream_t stream){
  const float* x   = (const float*)d_in[0];
  const float* c1i = (const float*)d_in[1];
  const float* h1i = (const float*)d_in[2];
  const float* c2i = (const float*)d_in[3];
  const float* h2i = (const float*)d_in[4];
  const float* Wi  = (const float*)d_in[5];
  const float* Wh  = (const float*)d_in[6];
  const float* bias= (const float*)d_in[7];
  const void* done_raw = d_in[8];
  const void* main_raw = d_in[9];
  float* out = (float*)d_out;

  char* ws = (char*)d_ws;
  size_t off=0;
  auto alloc=[&](size_t sz)->char*{ char* p = ws+off; off += (sz+255)&~(size_t)255; return p; };

  u16* xb   = (u16*)alloc(33554432ull*2);        // x as bf16 [32768][1024]
  u16* WiT  = (u16*)alloc(4096ull*1024*2);       // Wi^T bf16 [4096][1024]
  u16* WhT  = (u16*)alloc(4096ull*1024*2);       // Wh^T bf16 [4096][1024]
  u16* hs0  = (u16*)alloc(262144ull*2);
  u16* hs1  = (u16*)alloc(262144ull*2);
  u8* dmask = (u8*)alloc(32768);
  u8* mmask = (u8*)alloc(32768);
  int* flag = (int*)alloc(256);
  int* ready= (int*)alloc(1024);
  u16* Zx   = (u16*)alloc(268435456ull);         // Zx f16 [32768][4096] -- L3-resident

  detect_mask_mode<<<1,256,0,stream>>>((const u8*)done_raw, 32768, flag);
  convert_masks<<<64,256,0,stream>>>(done_raw, main_raw, dmask, mmask, 32768, flag);
  cvt_f32_bf16<<<32768,256,0,stream>>>(x, xb, 8388608);
  transpose_to_bf16<<<dim3(64,16),256,0,stream>>>(Wi, WiT, 1024, 4096);
  transpose_to_bf16<<<dim3(64,16),256,0,stream>>>(Wh, WhT, 1024, 4096);
  init_hsel<<<1024,256,0,stream>>>(h1i, h2i, mmask, hs0);
  zero_flags<<<1,256,0,stream>>>(ready, 256);

  gemm_zx<<<8192,256,0,stream>>>(xb, WiT, bias, Zx);

  lstm_persist<<<256,512,0,stream>>>(Zx,WhT,hs0,hs1,c1i,h1i,c2i,h2i,dmask,mmask,out,ready);
}